// Round 15
// baseline (235.788 us; speedup 1.0000x reference)
//
#include <hip/hip_runtime.h>

#define NN 100000
#define NE 1600000
#define FD 128
#define NC 40
#define NBK 782            // ceil(NN/128) buckets of 128 nodes
#define HISTB 256          // histogram / scatter blocks
#define CONVB 512          // bf16-convert blocks fused into P1
#define PREPB 276          // weight-split blocks fused into P1
#define CHUNK (NE / HISTB) // 6250 edges per block (exact)

typedef __attribute__((ext_vector_type(8))) short short8;
typedef __attribute__((ext_vector_type(4))) float f32x4;

// ---- workspace layout (bytes) ----
#define WS_OFF      0u          // (NN+1) int
#define WS_INVDEG   400384u     // NN float
#define WS_CNT      800512u     // [HISTB][NBK] int
#define WS_BTOT     1601280u    // NBK int
#define WS_BKO      1604480u    // (NBK+1) int
#define WS_WB       1607680u    // split weights + Wc bf16
#define WS_CSR      1880576u    // NE int (6.4 MB)
#define WS_XB       8280576u    // NN*FD bf16 (25.6 MB)
#define WS_MB       33880576u   // NN*FD bf16 mean
#define WS_HB       59480576u   // NN*FD bf16 h1; aliases u32 bval[NE] during build

__device__ inline unsigned short bf16_rne(float v) {
    union { float f; unsigned u; } a; a.f = v;
    return (unsigned short)((a.u + 0x7FFFu + ((a.u >> 16) & 1u)) >> 16);
}

__device__ inline void cvt_split(float v, unsigned short& h, unsigned short& l) {
    union { float f; unsigned u; } a; a.f = v;
    unsigned rh = (a.u + 0x7FFFu + ((a.u >> 16) & 1u)) >> 16;
    h = (unsigned short)rh;
    union { unsigned u; float f; } b; b.u = rh << 16;
    float lo = v - b.f;
    union { float f; unsigned u; } c; c.f = lo;
    l = (unsigned short)((c.u + 0x7FFFu + ((c.u >> 16) & 1u)) >> 16);
}

// ---------------- P1: fused bf16 convert + bucket histogram + weight split --
__global__ __launch_bounds__(256) void k_p1(
        const int* __restrict__ ei, int* __restrict__ cnt,
        const float* __restrict__ x, unsigned short* __restrict__ xb,
        const float* __restrict__ W1l, const float* __restrict__ W1r,
        const float* __restrict__ W2l, const float* __restrict__ W2r,
        const float* __restrict__ Wc, unsigned short* __restrict__ wb) {
    if (blockIdx.x < CONVB) {
        int i = blockIdx.x * 256 + threadIdx.x;
        const int total = NN * FD / 8;
        for (int s = i; s < total; s += CONVB * 256) {
            float4 a = *reinterpret_cast<const float4*>(x + (size_t)s * 8);
            float4 b = *reinterpret_cast<const float4*>(x + (size_t)s * 8 + 4);
            short8 o;
            o[0] = (short)bf16_rne(a.x); o[1] = (short)bf16_rne(a.y);
            o[2] = (short)bf16_rne(a.z); o[3] = (short)bf16_rne(a.w);
            o[4] = (short)bf16_rne(b.x); o[5] = (short)bf16_rne(b.y);
            o[6] = (short)bf16_rne(b.z); o[7] = (short)bf16_rne(b.w);
            *reinterpret_cast<short8*>(xb + (size_t)s * 8) = o;
        }
    } else if (blockIdx.x < CONVB + HISTB) {
        __shared__ int hist[NBK];
        const int* dst = ei + NE;
        int blk = blockIdx.x - CONVB;
        for (int j = threadIdx.x; j < NBK; j += 256) hist[j] = 0;
        __syncthreads();
        int base = blk * CHUNK;
        for (int i = threadIdx.x; i < CHUNK; i += 256)
            atomicAdd(&hist[dst[base + i] >> 7], 1);
        __syncthreads();
        for (int j = threadIdx.x; j < NBK; j += 256)
            cnt[blk * NBK + j] = hist[j];
    } else {
        int i = (blockIdx.x - CONVB - HISTB) * 256 + threadIdx.x;
        if (i < 65536) {
            int m = i >> 14, e = i & 16383;
            const float* W = (m == 0) ? W1l : (m == 1) ? W1r : (m == 2) ? W2l : W2r;
            unsigned short h, l;
            cvt_split(W[e], h, l);
            wb[m * 32768 + e] = h;
            wb[m * 32768 + 16384 + e] = l;
        } else if (i < 65536 + NC * FD) {
            int j = i - 65536;
            wb[131072 + j] = bf16_rne(Wc[j]);
        }
    }
}

// ---------------- P2a: per-bucket exclusive scan over blocks ----------------
__global__ __launch_bounds__(256) void k_p2a(int* __restrict__ cnt,
                                             int* __restrict__ btot) {
    __shared__ int s[256];
    int b = blockIdx.x, t = threadIdx.x;
    int v = cnt[t * NBK + b];
    s[t] = v;
    __syncthreads();
    for (int d = 1; d < 256; d <<= 1) {
        int x = (t >= d) ? s[t - d] : 0;
        __syncthreads();
        s[t] += x;
        __syncthreads();
    }
    cnt[t * NBK + b] = s[t] - v;
    if (t == 255) btot[b] = s[255];
}

// ---------------- P3: scatter into bucket-major bval (local bko scan) ------
__global__ __launch_bounds__(256) void k_p3(const int* __restrict__ ei,
                                            const int* __restrict__ cnt,
                                            const int* __restrict__ btot,
                                            int* __restrict__ bko,
                                            unsigned* __restrict__ bval) {
    __shared__ int bko_s[NBK + 1];
    __shared__ int cur[NBK];
    __shared__ int s[256];
    int t = threadIdx.x;
    int base = t * 4;
    int v[4]; int tsum = 0;
#pragma unroll
    for (int j = 0; j < 4; ++j) {
        int idx = base + j;
        v[j] = (idx < NBK) ? btot[idx] : 0;
        tsum += v[j];
    }
    s[t] = tsum;
    __syncthreads();
    for (int d = 1; d < 256; d <<= 1) {
        int x = (t >= d) ? s[t - d] : 0;
        __syncthreads();
        s[t] += x;
        __syncthreads();
    }
    int p = s[t] - tsum;
#pragma unroll
    for (int j = 0; j < 4; ++j) {
        int idx = base + j;
        if (idx <= NBK) bko_s[idx] = p;
        p += v[j];
    }
    __syncthreads();
    int blk = blockIdx.x;
    if (blk == 0) {
        for (int j = t; j <= NBK; j += 256) bko[j] = bko_s[j];
    }
    for (int j = t; j < NBK; j += 256)
        cur[j] = bko_s[j] + cnt[blk * NBK + j];
    __syncthreads();
    int ebase = blk * CHUNK;
    const int* src = ei;
    const int* dst = ei + NE;
    for (int i = t; i < CHUNK; i += 256) {
        int sv = src[ebase + i];
        int d  = dst[ebase + i];
        int pos = atomicAdd(&cur[d >> 7], 1);
        bval[pos] = (unsigned)sv | ((unsigned)(d & 127) << 17);
    }
}

// ---------------- P4: per-bucket counting sort -> csr, off, invdeg ---------
__global__ __launch_bounds__(256) void k_p4(const unsigned* __restrict__ bval,
                                            const int* __restrict__ bko,
                                            int* __restrict__ csr,
                                            int* __restrict__ off,
                                            float* __restrict__ invdeg) {
    __shared__ int hist[128], curk[128], sc[128];
    int b = blockIdx.x, tid = threadIdx.x;
    int s = bko[b], e = bko[b + 1];
    if (tid < 128) hist[tid] = 0;
    __syncthreads();
    for (int i = s + tid; i < e; i += 256)
        atomicAdd(&hist[bval[i] >> 17], 1);
    __syncthreads();
    if (tid < 128) sc[tid] = hist[tid];
    __syncthreads();
    for (int d = 1; d < 128; d <<= 1) {
        int x = (tid >= d && tid < 128) ? sc[tid - d] : 0;
        __syncthreads();
        if (tid < 128) sc[tid] += x;
        __syncthreads();
    }
    if (tid < 128) {
        int excl = sc[tid] - hist[tid];
        curk[tid] = excl;
        int node = b * 128 + tid;
        if (node < NN) {
            off[node] = s + excl;
            int dg = hist[tid];
            invdeg[node] = 1.0f / (float)(dg > 0 ? dg : 1);
        }
    }
    if (b == 0 && tid == 0) off[NN] = NE;
    __syncthreads();
    for (int i = s + tid; i < e; i += 256) {
        unsigned v = bval[i];
        int dl = v >> 17;
        int r = atomicAdd(&curk[dl], 1);
        csr[s + r] = (int)(v & 0x1FFFFu);
    }
}

// ---------------- mean aggregation: wave/node, depth-4 gather pipeline -----
__device__ inline void acc8(float* a, uint4 v) {
    a[0] += __uint_as_float(v.x << 16);
    a[1] += __uint_as_float(v.x & 0xFFFF0000u);
    a[2] += __uint_as_float(v.y << 16);
    a[3] += __uint_as_float(v.y & 0xFFFF0000u);
    a[4] += __uint_as_float(v.z << 16);
    a[5] += __uint_as_float(v.z & 0xFFFF0000u);
    a[6] += __uint_as_float(v.w << 16);
    a[7] += __uint_as_float(v.w & 0xFFFF0000u);
}

__global__ __launch_bounds__(256) void k_agg(const unsigned short* __restrict__ Xb,
                                             const int* __restrict__ off,
                                             const int* __restrict__ csr,
                                             const float* __restrict__ invdeg,
                                             unsigned short* __restrict__ Mb) {
    int wid = (blockIdx.x * 256 + threadIdx.x) >> 6;
    int lane = threadIdx.x & 63;
    if (wid >= NN) return;
    const int g  = lane >> 4;
    const int fc = lane & 15;
    const unsigned short* Xl = Xb + fc * 8;
    int s0 = off[wid], s1 = off[wid + 1];
    float a[8] = {};
    int e = s0;
    if (e + 15 < s1) {
        uint4 p0 = *reinterpret_cast<const uint4*>(Xl + ((size_t)csr[e + g]      << 7));
        uint4 p1 = *reinterpret_cast<const uint4*>(Xl + ((size_t)csr[e + 4 + g]  << 7));
        uint4 p2 = *reinterpret_cast<const uint4*>(Xl + ((size_t)csr[e + 8 + g]  << 7));
        uint4 p3 = *reinterpret_cast<const uint4*>(Xl + ((size_t)csr[e + 12 + g] << 7));
        for (e += 16; e + 15 < s1; e += 16) {
            int j0 = csr[e + g];
            int j1 = csr[e + 4 + g];
            int j2 = csr[e + 8 + g];
            int j3 = csr[e + 12 + g];
            uint4 n0 = *reinterpret_cast<const uint4*>(Xl + ((size_t)j0 << 7));
            uint4 n1 = *reinterpret_cast<const uint4*>(Xl + ((size_t)j1 << 7));
            uint4 n2 = *reinterpret_cast<const uint4*>(Xl + ((size_t)j2 << 7));
            uint4 n3 = *reinterpret_cast<const uint4*>(Xl + ((size_t)j3 << 7));
            acc8(a, p0); acc8(a, p1); acc8(a, p2); acc8(a, p3);
            p0 = n0; p1 = n1; p2 = n2; p3 = n3;
        }
        acc8(a, p0); acc8(a, p1); acc8(a, p2); acc8(a, p3);
    }
    for (; e + 7 < s1; e += 8) {
        int r0 = csr[e + g];
        int r1 = csr[e + 4 + g];
        uint4 v0 = *reinterpret_cast<const uint4*>(Xl + ((size_t)r0 << 7));
        uint4 v1 = *reinterpret_cast<const uint4*>(Xl + ((size_t)r1 << 7));
        acc8(a, v0);
        acc8(a, v1);
    }
    for (; e < s1; e += 4) {
        int cnt = s1 - e;
        int r = csr[e + (g < cnt ? g : 0)];
        uint4 v = *reinterpret_cast<const uint4*>(Xl + ((size_t)r << 7));
        if (g < cnt) acc8(a, v);
    }
#pragma unroll
    for (int j = 0; j < 8; ++j) {
        a[j] += __shfl_xor(a[j], 32);
        a[j] += __shfl_xor(a[j], 16);
    }
    if (g == 0) {
        float w = invdeg[wid];
        uint4 o;
        o.x = (unsigned)bf16_rne(a[0] * w) | ((unsigned)bf16_rne(a[1] * w) << 16);
        o.y = (unsigned)bf16_rne(a[2] * w) | ((unsigned)bf16_rne(a[3] * w) << 16);
        o.z = (unsigned)bf16_rne(a[4] * w) | ((unsigned)bf16_rne(a[5] * w) << 16);
        o.w = (unsigned)bf16_rne(a[6] * w) | ((unsigned)bf16_rne(a[7] * w) << 16);
        *reinterpret_cast<uint4*>(Mb + (size_t)wid * FD + fc * 8) = o;
    }
}

// ---------------- dual GEMM via MFMA, 128x128 tile (+fused classifier) -----
// Block = 128 nodes x 128 outs, 4 waves (wave w -> rows w*32..w*32+31, all cols).
// A-fragments loaded DIRECT from global (layout row=l15, k=kb*8 matches MFMA);
// LDS holds only the weight chunk (hi+lo). W pre-split hi/lo.
template <bool FUSE>
__global__ __launch_bounds__(256, 3) void k_gemm(
        const unsigned short* __restrict__ M,
        const unsigned short* __restrict__ X,
        const unsigned short* __restrict__ Wl,
        const unsigned short* __restrict__ Wr,
        const float* __restrict__ bias,
        const unsigned short* __restrict__ Wcb,
        const float* __restrict__ bc,
        unsigned short* outb, float* outf) {
    __shared__ __align__(16) unsigned short pool[FUSE ? 22848 : 10240];
    unsigned short* Bh = pool;            // [128][40]
    unsigned short* Bl = pool + 5120;     // [128][40]

    const int tid = threadIdx.x;
    const int wave = tid >> 6;
    const int lane = tid & 63;
    const int nb = blockIdx.x * 128;
    const int l15 = lane & 15;
    const int kb = lane >> 4;

    f32x4 acc[2][8] = {};

    for (int c = 0; c < 8; ++c) {
        const unsigned short* A = (c < 4) ? M : X;
        const unsigned short* W = (c < 4) ? Wl : Wr;
        const int kc = (c & 3) * 32;
        // A-fragments: direct global (independent of LDS barriers)
        short8 a[2];
#pragma unroll
        for (int mt = 0; mt < 2; ++mt) {
            int gn = nb + wave * 32 + mt * 16 + l15;
            a[mt] = (gn < NN)
                ? *reinterpret_cast<const short8*>(A + (size_t)gn * FD + kc + kb * 8)
                : short8{};
        }
        __syncthreads();   // previous chunk's B reads done
        // stage W chunk: 512 slots (o,seg), 2 slots/thread, hi+lo
#pragma unroll
        for (int r = 0; r < 2; ++r) {
            int slot = tid + 256 * r;
            int o = slot >> 2, seg = slot & 3;
            short8 vh = *reinterpret_cast<const short8*>(W + o * FD + kc + seg * 8);
            short8 vl = *reinterpret_cast<const short8*>(W + 16384 + o * FD + kc + seg * 8);
            *reinterpret_cast<short8*>(&Bh[o * 40 + seg * 8]) = vh;
            *reinterpret_cast<short8*>(&Bl[o * 40 + seg * 8]) = vl;
        }
        __syncthreads();
#pragma unroll
        for (int nt = 0; nt < 8; ++nt) {
            int o = nt * 16 + l15;
            short8 b_h = *reinterpret_cast<const short8*>(&Bh[o * 40 + kb * 8]);
            short8 b_l = *reinterpret_cast<const short8*>(&Bl[o * 40 + kb * 8]);
#pragma unroll
            for (int mt = 0; mt < 2; ++mt) {
                acc[mt][nt] = __builtin_amdgcn_mfma_f32_16x16x32_bf16(a[mt], b_h, acc[mt][nt], 0, 0, 0);
                acc[mt][nt] = __builtin_amdgcn_mfma_f32_16x16x32_bf16(a[mt], b_l, acc[mt][nt], 0, 0, 0);
            }
        }
    }

    float bz[8];
#pragma unroll
    for (int nt = 0; nt < 8; ++nt) bz[nt] = bias[nt * 16 + l15];

    if (!FUSE) {
#pragma unroll
        for (int mt = 0; mt < 2; ++mt) {
            int gn0 = nb + wave * 32 + mt * 16 + kb * 4;
#pragma unroll
            for (int r = 0; r < 4; ++r) {
                int gn = gn0 + r;
                if (gn < NN) {
#pragma unroll
                    for (int nt = 0; nt < 8; ++nt) {
                        float v = fmaxf(acc[mt][nt][r] + bz[nt], 0.f);
                        outb[(size_t)gn * FD + nt * 16 + l15] = bf16_rne(v);
                    }
                }
            }
        }
    } else {
        unsigned short* Hs  = pool;           // [128][136] (aliases Bh/Bl - done)
        unsigned short* Wcs = pool + 17408;   // [40][136]
        __syncthreads();   // all waves done reading Bh/Bl
        // stage Wc bf16: 640 slots (40 rows x 16 segs)
#pragma unroll
        for (int r = 0; r < 3; ++r) {
            int slot = tid + 256 * r;
            if (slot < 640) {
                int row = slot >> 4, seg = slot & 15;
                *reinterpret_cast<short8*>(&Wcs[row * 136 + seg * 8]) =
                    *reinterpret_cast<const short8*>(Wcb + row * FD + seg * 8);
            }
        }
        // stage h2 tile (relu + bf16)
#pragma unroll
        for (int mt = 0; mt < 2; ++mt) {
            int row0 = wave * 32 + mt * 16 + kb * 4;
#pragma unroll
            for (int r = 0; r < 4; ++r) {
#pragma unroll
                for (int nt = 0; nt < 8; ++nt) {
                    float v = fmaxf(acc[mt][nt][r] + bz[nt], 0.f);
                    Hs[(row0 + r) * 136 + nt * 16 + l15] = bf16_rne(v);
                }
            }
        }
        __syncthreads();
        // mini-GEMM: wave w -> rows w*32..+31 (2 tiles), cols 0..47 (3 tiles), K=128
        f32x4 c2[2][3] = {};
#pragma unroll
        for (int kk = 0; kk < 4; ++kk) {
#pragma unroll
            for (int rt = 0; rt < 2; ++rt) {
                short8 af = *reinterpret_cast<const short8*>(
                    &Hs[(wave * 32 + rt * 16 + l15) * 136 + kk * 32 + kb * 8]);
#pragma unroll
                for (int t = 0; t < 3; ++t) {
                    short8 bf = *reinterpret_cast<const short8*>(
                        &Wcs[(t * 16 + l15) * 136 + kk * 32 + kb * 8]);
                    c2[rt][t] = __builtin_amdgcn_mfma_f32_16x16x32_bf16(af, bf, c2[rt][t], 0, 0, 0);
                }
            }
        }
#pragma unroll
        for (int rt = 0; rt < 2; ++rt) {
#pragma unroll
            for (int t = 0; t < 3; ++t) {
                int cls = t * 16 + l15;
                if (cls < NC) {
#pragma unroll
                    for (int r = 0; r < 4; ++r) {
                        int gn = nb + wave * 32 + rt * 16 + kb * 4 + r;
                        if (gn < NN)
                            outf[(size_t)gn * NC + cls] = c2[rt][t][r] + bc[cls];
                    }
                }
            }
        }
    }
}

extern "C" void kernel_launch(void* const* d_in, const int* in_sizes, int n_in,
                              void* d_out, int out_size, void* d_ws, size_t ws_size,
                              hipStream_t stream) {
    const float* x   = (const float*)d_in[0];
    const int*   ei  = (const int*)d_in[1];
    const float* W1l = (const float*)d_in[3];
    const float* b1l = (const float*)d_in[4];
    const float* W1r = (const float*)d_in[5];
    const float* W2l = (const float*)d_in[6];
    const float* b2l = (const float*)d_in[7];
    const float* W2r = (const float*)d_in[8];
    const float* Wc  = (const float*)d_in[9];
    const float* bc  = (const float*)d_in[10];
    float* out = (float*)d_out;

    char* ws = (char*)d_ws;
    int*   off    = (int*)(ws + WS_OFF);
    float* invdeg = (float*)(ws + WS_INVDEG);
    int*   cnt    = (int*)(ws + WS_CNT);
    int*   btot   = (int*)(ws + WS_BTOT);
    int*   bko    = (int*)(ws + WS_BKO);
    unsigned short* wb = (unsigned short*)(ws + WS_WB);
    int*   csr    = (int*)(ws + WS_CSR);
    unsigned short* xb = (unsigned short*)(ws + WS_XB);
    unsigned short* mb = (unsigned short*)(ws + WS_MB);
    unsigned short* hb = (unsigned short*)(ws + WS_HB);
    unsigned* bval = (unsigned*)(ws + WS_HB);  // consumed by k_p4 before hb written

    k_p1<<<CONVB + HISTB + PREPB, 256, 0, stream>>>(ei, cnt, x, xb,
                                                    W1l, W1r, W2l, W2r, Wc, wb);
    k_p2a<<<NBK, 256, 0, stream>>>(cnt, btot);
    k_p3<<<HISTB, 256, 0, stream>>>(ei, cnt, btot, bko, bval);
    k_p4<<<NBK, 256, 0, stream>>>(bval, bko, csr, off, invdeg);

    const int GG = (NN + 127) / 128;   // 782

    // layer 1
    k_agg<<<(NN + 3) / 4, 256, 0, stream>>>(xb, off, csr, invdeg, mb);
    k_gemm<false><<<GG, 256, 0, stream>>>(mb, xb, wb, wb + 32768, b1l,
                                          nullptr, nullptr, hb, nullptr);
    // layer 2 + fused classifier
    k_agg<<<(NN + 3) / 4, 256, 0, stream>>>(hb, off, csr, invdeg, mb);
    k_gemm<true><<<GG, 256, 0, stream>>>(mb, hb, wb + 65536, wb + 98304, b2l,
                                         wb + 131072, bc, nullptr, out);
}

// Round 16
// 233.598 us; speedup vs baseline: 1.0094x; 1.0094x over previous
//
#include <hip/hip_runtime.h>

#define NN 100000
#define NE 1600000
#define FD 128
#define NC 40
#define NBK 782            // ceil(NN/128) buckets of 128 nodes
#define HISTB 256          // histogram / scatter blocks
#define CONVB 512          // bf16-convert blocks fused into P1
#define PREPB 276          // weight-split blocks fused into P1
#define CHUNK (NE / HISTB) // 6250 edges per block (exact)

typedef __attribute__((ext_vector_type(8))) short short8;
typedef __attribute__((ext_vector_type(4))) float f32x4;

// ---- workspace layout (bytes) ----
#define WS_OFF      0u          // (NN+1) int
#define WS_INVDEG   400384u     // NN float
#define WS_CNT      800512u     // [HISTB][NBK] int
#define WS_BTOT     1601280u    // NBK int
#define WS_BKO      1604480u    // (NBK+1) int
#define WS_WB       1607680u    // split weights + Wc bf16
#define WS_CSR      1880576u    // NE int (6.4 MB)
#define WS_XB       8280576u    // NN*FD bf16 (25.6 MB)
#define WS_MB       33880576u   // NN*FD bf16 mean
#define WS_HB       59480576u   // NN*FD bf16 h1; aliases u32 bval[NE] during build

__device__ inline unsigned short bf16_rne(float v) {
    union { float f; unsigned u; } a; a.f = v;
    return (unsigned short)((a.u + 0x7FFFu + ((a.u >> 16) & 1u)) >> 16);
}

__device__ inline void cvt_split(float v, unsigned short& h, unsigned short& l) {
    union { float f; unsigned u; } a; a.f = v;
    unsigned rh = (a.u + 0x7FFFu + ((a.u >> 16) & 1u)) >> 16;
    h = (unsigned short)rh;
    union { unsigned u; float f; } b; b.u = rh << 16;
    float lo = v - b.f;
    union { float f; unsigned u; } c; c.f = lo;
    l = (unsigned short)((c.u + 0x7FFFu + ((c.u >> 16) & 1u)) >> 16);
}

// ---------------- P1: fused bf16 convert + bucket histogram + weight split --
__global__ __launch_bounds__(256) void k_p1(
        const int* __restrict__ ei, int* __restrict__ cnt,
        const float* __restrict__ x, unsigned short* __restrict__ xb,
        const float* __restrict__ W1l, const float* __restrict__ W1r,
        const float* __restrict__ W2l, const float* __restrict__ W2r,
        const float* __restrict__ Wc, unsigned short* __restrict__ wb) {
    if (blockIdx.x < CONVB) {
        int i = blockIdx.x * 256 + threadIdx.x;
        const int total = NN * FD / 8;
        for (int s = i; s < total; s += CONVB * 256) {
            float4 a = *reinterpret_cast<const float4*>(x + (size_t)s * 8);
            float4 b = *reinterpret_cast<const float4*>(x + (size_t)s * 8 + 4);
            short8 o;
            o[0] = (short)bf16_rne(a.x); o[1] = (short)bf16_rne(a.y);
            o[2] = (short)bf16_rne(a.z); o[3] = (short)bf16_rne(a.w);
            o[4] = (short)bf16_rne(b.x); o[5] = (short)bf16_rne(b.y);
            o[6] = (short)bf16_rne(b.z); o[7] = (short)bf16_rne(b.w);
            *reinterpret_cast<short8*>(xb + (size_t)s * 8) = o;
        }
    } else if (blockIdx.x < CONVB + HISTB) {
        __shared__ int hist[NBK];
        const int* dst = ei + NE;
        int blk = blockIdx.x - CONVB;
        for (int j = threadIdx.x; j < NBK; j += 256) hist[j] = 0;
        __syncthreads();
        int base = blk * CHUNK;
        for (int i = threadIdx.x; i < CHUNK; i += 256)
            atomicAdd(&hist[dst[base + i] >> 7], 1);
        __syncthreads();
        for (int j = threadIdx.x; j < NBK; j += 256)
            cnt[blk * NBK + j] = hist[j];
    } else {
        int i = (blockIdx.x - CONVB - HISTB) * 256 + threadIdx.x;
        if (i < 65536) {
            int m = i >> 14, e = i & 16383;
            const float* W = (m == 0) ? W1l : (m == 1) ? W1r : (m == 2) ? W2l : W2r;
            unsigned short h, l;
            cvt_split(W[e], h, l);
            wb[m * 32768 + e] = h;
            wb[m * 32768 + 16384 + e] = l;
        } else if (i < 65536 + NC * FD) {
            int j = i - 65536;
            wb[131072 + j] = bf16_rne(Wc[j]);
        }
    }
}

// ---------------- P2a: per-bucket exclusive scan over blocks ----------------
__global__ __launch_bounds__(256) void k_p2a(int* __restrict__ cnt,
                                             int* __restrict__ btot) {
    __shared__ int s[256];
    int b = blockIdx.x, t = threadIdx.x;
    int v = cnt[t * NBK + b];
    s[t] = v;
    __syncthreads();
    for (int d = 1; d < 256; d <<= 1) {
        int x = (t >= d) ? s[t - d] : 0;
        __syncthreads();
        s[t] += x;
        __syncthreads();
    }
    cnt[t * NBK + b] = s[t] - v;
    if (t == 255) btot[b] = s[255];
}

// ---------------- P3: scatter into bucket-major bval (local bko scan) ------
__global__ __launch_bounds__(256) void k_p3(const int* __restrict__ ei,
                                            const int* __restrict__ cnt,
                                            const int* __restrict__ btot,
                                            int* __restrict__ bko,
                                            unsigned* __restrict__ bval) {
    __shared__ int bko_s[NBK + 1];
    __shared__ int cur[NBK];
    __shared__ int s[256];
    int t = threadIdx.x;
    int base = t * 4;
    int v[4]; int tsum = 0;
#pragma unroll
    for (int j = 0; j < 4; ++j) {
        int idx = base + j;
        v[j] = (idx < NBK) ? btot[idx] : 0;
        tsum += v[j];
    }
    s[t] = tsum;
    __syncthreads();
    for (int d = 1; d < 256; d <<= 1) {
        int x = (t >= d) ? s[t - d] : 0;
        __syncthreads();
        s[t] += x;
        __syncthreads();
    }
    int p = s[t] - tsum;
#pragma unroll
    for (int j = 0; j < 4; ++j) {
        int idx = base + j;
        if (idx <= NBK) bko_s[idx] = p;
        p += v[j];
    }
    __syncthreads();
    int blk = blockIdx.x;
    if (blk == 0) {
        for (int j = t; j <= NBK; j += 256) bko[j] = bko_s[j];
    }
    for (int j = t; j < NBK; j += 256)
        cur[j] = bko_s[j] + cnt[blk * NBK + j];
    __syncthreads();
    int ebase = blk * CHUNK;
    const int* src = ei;
    const int* dst = ei + NE;
    for (int i = t; i < CHUNK; i += 256) {
        int sv = src[ebase + i];
        int d  = dst[ebase + i];
        int pos = atomicAdd(&cur[d >> 7], 1);
        bval[pos] = (unsigned)sv | ((unsigned)(d & 127) << 17);
    }
}

// ---------------- P4: per-bucket counting sort -> csr, off, invdeg ---------
__global__ __launch_bounds__(256) void k_p4(const unsigned* __restrict__ bval,
                                            const int* __restrict__ bko,
                                            int* __restrict__ csr,
                                            int* __restrict__ off,
                                            float* __restrict__ invdeg) {
    __shared__ int hist[128], curk[128], sc[128];
    int b = blockIdx.x, tid = threadIdx.x;
    int s = bko[b], e = bko[b + 1];
    if (tid < 128) hist[tid] = 0;
    __syncthreads();
    for (int i = s + tid; i < e; i += 256)
        atomicAdd(&hist[bval[i] >> 17], 1);
    __syncthreads();
    if (tid < 128) sc[tid] = hist[tid];
    __syncthreads();
    for (int d = 1; d < 128; d <<= 1) {
        int x = (tid >= d && tid < 128) ? sc[tid - d] : 0;
        __syncthreads();
        if (tid < 128) sc[tid] += x;
        __syncthreads();
    }
    if (tid < 128) {
        int excl = sc[tid] - hist[tid];
        curk[tid] = excl;
        int node = b * 128 + tid;
        if (node < NN) {
            off[node] = s + excl;
            int dg = hist[tid];
            invdeg[node] = 1.0f / (float)(dg > 0 ? dg : 1);
        }
    }
    if (b == 0 && tid == 0) off[NN] = NE;
    __syncthreads();
    for (int i = s + tid; i < e; i += 256) {
        unsigned v = bval[i];
        int dl = v >> 17;
        int r = atomicAdd(&curk[dl], 1);
        csr[s + r] = (int)(v & 0x1FFFFu);
    }
}

// ---------------- mean aggregation: wave/node, depth-4 gather pipeline -----
__device__ inline void acc8(float* a, uint4 v) {
    a[0] += __uint_as_float(v.x << 16);
    a[1] += __uint_as_float(v.x & 0xFFFF0000u);
    a[2] += __uint_as_float(v.y << 16);
    a[3] += __uint_as_float(v.y & 0xFFFF0000u);
    a[4] += __uint_as_float(v.z << 16);
    a[5] += __uint_as_float(v.z & 0xFFFF0000u);
    a[6] += __uint_as_float(v.w << 16);
    a[7] += __uint_as_float(v.w & 0xFFFF0000u);
}

__global__ __launch_bounds__(256) void k_agg(const unsigned short* __restrict__ Xb,
                                             const int* __restrict__ off,
                                             const int* __restrict__ csr,
                                             const float* __restrict__ invdeg,
                                             unsigned short* __restrict__ Mb) {
    int wid = (blockIdx.x * 256 + threadIdx.x) >> 6;
    int lane = threadIdx.x & 63;
    if (wid >= NN) return;
    const int g  = lane >> 4;
    const int fc = lane & 15;
    const unsigned short* Xl = Xb + fc * 8;
    int s0 = off[wid], s1 = off[wid + 1];
    float a[8] = {};
    int e = s0;
    if (e + 15 < s1) {
        uint4 p0 = *reinterpret_cast<const uint4*>(Xl + ((size_t)csr[e + g]      << 7));
        uint4 p1 = *reinterpret_cast<const uint4*>(Xl + ((size_t)csr[e + 4 + g]  << 7));
        uint4 p2 = *reinterpret_cast<const uint4*>(Xl + ((size_t)csr[e + 8 + g]  << 7));
        uint4 p3 = *reinterpret_cast<const uint4*>(Xl + ((size_t)csr[e + 12 + g] << 7));
        for (e += 16; e + 15 < s1; e += 16) {
            int j0 = csr[e + g];
            int j1 = csr[e + 4 + g];
            int j2 = csr[e + 8 + g];
            int j3 = csr[e + 12 + g];
            uint4 n0 = *reinterpret_cast<const uint4*>(Xl + ((size_t)j0 << 7));
            uint4 n1 = *reinterpret_cast<const uint4*>(Xl + ((size_t)j1 << 7));
            uint4 n2 = *reinterpret_cast<const uint4*>(Xl + ((size_t)j2 << 7));
            uint4 n3 = *reinterpret_cast<const uint4*>(Xl + ((size_t)j3 << 7));
            acc8(a, p0); acc8(a, p1); acc8(a, p2); acc8(a, p3);
            p0 = n0; p1 = n1; p2 = n2; p3 = n3;
        }
        acc8(a, p0); acc8(a, p1); acc8(a, p2); acc8(a, p3);
    }
    for (; e + 7 < s1; e += 8) {
        int r0 = csr[e + g];
        int r1 = csr[e + 4 + g];
        uint4 v0 = *reinterpret_cast<const uint4*>(Xl + ((size_t)r0 << 7));
        uint4 v1 = *reinterpret_cast<const uint4*>(Xl + ((size_t)r1 << 7));
        acc8(a, v0);
        acc8(a, v1);
    }
    for (; e < s1; e += 4) {
        int cnt = s1 - e;
        int r = csr[e + (g < cnt ? g : 0)];
        uint4 v = *reinterpret_cast<const uint4*>(Xl + ((size_t)r << 7));
        if (g < cnt) acc8(a, v);
    }
#pragma unroll
    for (int j = 0; j < 8; ++j) {
        a[j] += __shfl_xor(a[j], 32);
        a[j] += __shfl_xor(a[j], 16);
    }
    if (g == 0) {
        float w = invdeg[wid];
        uint4 o;
        o.x = (unsigned)bf16_rne(a[0] * w) | ((unsigned)bf16_rne(a[1] * w) << 16);
        o.y = (unsigned)bf16_rne(a[2] * w) | ((unsigned)bf16_rne(a[3] * w) << 16);
        o.z = (unsigned)bf16_rne(a[4] * w) | ((unsigned)bf16_rne(a[5] * w) << 16);
        o.w = (unsigned)bf16_rne(a[6] * w) | ((unsigned)bf16_rne(a[7] * w) << 16);
        *reinterpret_cast<uint4*>(Mb + (size_t)wid * FD + fc * 8) = o;
    }
}

// ---------------- dual GEMM via MFMA (+fused classifier) ----------------
template <bool FUSE>
__global__ __launch_bounds__(256, 3) void k_gemm(
        const unsigned short* __restrict__ M,
        const unsigned short* __restrict__ X,
        const unsigned short* __restrict__ Wl,
        const unsigned short* __restrict__ Wr,
        const float* __restrict__ bias,
        const unsigned short* __restrict__ Wcb,
        const float* __restrict__ bc,
        unsigned short* outb, float* outf) {
    __shared__ __align__(16) unsigned short pool[FUSE ? 21504 : 12800];
    unsigned short* Ah = pool;            // [64][40]
    unsigned short* Bh = pool + 2560;     // [128][40]
    unsigned short* Bl = pool + 7680;     // [128][40]

    const int tid = threadIdx.x;
    const int wave = tid >> 6;
    const int lane = tid & 63;
    const int wm = wave & 1;
    const int wn = wave >> 1;
    const int nb = blockIdx.x * 64;
    const int l15 = lane & 15;
    const int kb = lane >> 4;

    f32x4 acc[2][4] = {};

    for (int c = 0; c < 8; ++c) {
        const unsigned short* A = (c < 4) ? M : X;
        const unsigned short* W = (c < 4) ? Wl : Wr;
        const int kc = (c & 3) * 32;
        __syncthreads();
        {
            int row = tid >> 2, seg = tid & 3;
            int gn = nb + row;
            short8 v = {};
            if (gn < NN)
                v = *reinterpret_cast<const short8*>(A + (size_t)gn * FD + kc + seg * 8);
            *reinterpret_cast<short8*>(&Ah[row * 40 + seg * 8]) = v;
        }
#pragma unroll
        for (int r = 0; r < 2; ++r) {
            int slot = tid + 256 * r;     // < 512: 128 rows x 4 segs
            int o = slot >> 2, seg = slot & 3;
            short8 vh = *reinterpret_cast<const short8*>(W + o * FD + kc + seg * 8);
            short8 vl = *reinterpret_cast<const short8*>(W + 16384 + o * FD + kc + seg * 8);
            *reinterpret_cast<short8*>(&Bh[o * 40 + seg * 8]) = vh;
            *reinterpret_cast<short8*>(&Bl[o * 40 + seg * 8]) = vl;
        }
        __syncthreads();
        short8 a[2], b_h[4], b_l[4];
#pragma unroll
        for (int mt = 0; mt < 2; ++mt) {
            int row = wm * 32 + mt * 16 + l15;
            a[mt] = *reinterpret_cast<const short8*>(&Ah[row * 40 + kb * 8]);
        }
#pragma unroll
        for (int nt = 0; nt < 4; ++nt) {
            int o = wn * 64 + nt * 16 + l15;
            b_h[nt] = *reinterpret_cast<const short8*>(&Bh[o * 40 + kb * 8]);
            b_l[nt] = *reinterpret_cast<const short8*>(&Bl[o * 40 + kb * 8]);
        }
#pragma unroll
        for (int mt = 0; mt < 2; ++mt)
#pragma unroll
            for (int nt = 0; nt < 4; ++nt) {
                acc[mt][nt] = __builtin_amdgcn_mfma_f32_16x16x32_bf16(a[mt], b_h[nt], acc[mt][nt], 0, 0, 0);
                acc[mt][nt] = __builtin_amdgcn_mfma_f32_16x16x32_bf16(a[mt], b_l[nt], acc[mt][nt], 0, 0, 0);
            }
    }

    float bz[4];
#pragma unroll
    for (int nt = 0; nt < 4; ++nt) bz[nt] = bias[wn * 64 + nt * 16 + l15];

    if (!FUSE) {
#pragma unroll
        for (int mt = 0; mt < 2; ++mt) {
            int gn0 = nb + wm * 32 + mt * 16 + kb * 4;
#pragma unroll
            for (int r = 0; r < 4; ++r) {
                int gn = gn0 + r;
                if (gn < NN) {
#pragma unroll
                    for (int nt = 0; nt < 4; ++nt) {
                        float v = fmaxf(acc[mt][nt][r] + bz[nt], 0.f);
                        outb[(size_t)gn * FD + wn * 64 + nt * 16 + l15] = bf16_rne(v);
                    }
                }
            }
        }
    } else {
        unsigned short* Hs  = pool + 12800;   // [64][136]
        unsigned short* Wcs = pool;           // [40][136] (reuses staging)
        __syncthreads();
#pragma unroll
        for (int r = 0; r < 3; ++r) {
            int slot = tid + 256 * r;         // 640 slots: 40 rows x 16 segs
            if (slot < 640) {
                int row = slot >> 4, seg = slot & 15;
                *reinterpret_cast<short8*>(&Wcs[row * 136 + seg * 8]) =
                    *reinterpret_cast<const short8*>(Wcb + row * FD + seg * 8);
            }
        }
#pragma unroll
        for (int mt = 0; mt < 2; ++mt) {
            int row0 = wm * 32 + mt * 16 + kb * 4;
#pragma unroll
            for (int r = 0; r < 4; ++r) {
#pragma unroll
                for (int nt = 0; nt < 4; ++nt) {
                    float v = fmaxf(acc[mt][nt][r] + bz[nt], 0.f);
                    Hs[(row0 + r) * 136 + wn * 64 + nt * 16 + l15] = bf16_rne(v);
                }
            }
        }
        __syncthreads();
        f32x4 c2[3] = {};
#pragma unroll
        for (int kk = 0; kk < 4; ++kk) {
            short8 af = *reinterpret_cast<const short8*>(
                &Hs[(wave * 16 + l15) * 136 + kk * 32 + kb * 8]);
#pragma unroll
            for (int t = 0; t < 3; ++t) {
                short8 bf = *reinterpret_cast<const short8*>(
                    &Wcs[(t * 16 + l15) * 136 + kk * 32 + kb * 8]);
                c2[t] = __builtin_amdgcn_mfma_f32_16x16x32_bf16(af, bf, c2[t], 0, 0, 0);
            }
        }
#pragma unroll
        for (int t = 0; t < 3; ++t) {
            int cls = t * 16 + l15;
            if (cls < NC) {
#pragma unroll
                for (int r = 0; r < 4; ++r) {
                    int gn = nb + wave * 16 + kb * 4 + r;
                    if (gn < NN)
                        outf[(size_t)gn * NC + cls] = c2[t][r] + bc[cls];
                }
            }
        }
    }
}

extern "C" void kernel_launch(void* const* d_in, const int* in_sizes, int n_in,
                              void* d_out, int out_size, void* d_ws, size_t ws_size,
                              hipStream_t stream) {
    const float* x   = (const float*)d_in[0];
    const int*   ei  = (const int*)d_in[1];
    const float* W1l = (const float*)d_in[3];
    const float* b1l = (const float*)d_in[4];
    const float* W1r = (const float*)d_in[5];
    const float* W2l = (const float*)d_in[6];
    const float* b2l = (const float*)d_in[7];
    const float* W2r = (const float*)d_in[8];
    const float* Wc  = (const float*)d_in[9];
    const float* bc  = (const float*)d_in[10];
    float* out = (float*)d_out;

    char* ws = (char*)d_ws;
    int*   off    = (int*)(ws + WS_OFF);
    float* invdeg = (float*)(ws + WS_INVDEG);
    int*   cnt    = (int*)(ws + WS_CNT);
    int*   btot   = (int*)(ws + WS_BTOT);
    int*   bko    = (int*)(ws + WS_BKO);
    unsigned short* wb = (unsigned short*)(ws + WS_WB);
    int*   csr    = (int*)(ws + WS_CSR);
    unsigned short* xb = (unsigned short*)(ws + WS_XB);
    unsigned short* mb = (unsigned short*)(ws + WS_MB);
    unsigned short* hb = (unsigned short*)(ws + WS_HB);
    unsigned* bval = (unsigned*)(ws + WS_HB);  // consumed by k_p4 before hb written

    k_p1<<<CONVB + HISTB + PREPB, 256, 0, stream>>>(ei, cnt, x, xb,
                                                    W1l, W1r, W2l, W2r, Wc, wb);
    k_p2a<<<NBK, 256, 0, stream>>>(cnt, btot);
    k_p3<<<HISTB, 256, 0, stream>>>(ei, cnt, btot, bko, bval);
    k_p4<<<NBK, 256, 0, stream>>>(bval, bko, csr, off, invdeg);

    const int GG = (NN + 63) / 64;   // 1563

    // layer 1
    k_agg<<<(NN + 3) / 4, 256, 0, stream>>>(xb, off, csr, invdeg, mb);
    k_gemm<false><<<GG, 256, 0, stream>>>(mb, xb, wb, wb + 32768, b1l,
                                          nullptr, nullptr, hb, nullptr);
    // layer 2 + fused classifier
    k_agg<<<(NN + 3) / 4, 256, 0, stream>>>(hb, off, csr, invdeg, mb);
    k_gemm<true><<<GG, 256, 0, stream>>>(mb, hb, wb + 65536, wb + 98304, b2l,
                                         wb + 131072, bc, nullptr, out);
}